// Round 3
// baseline (97.641 us; speedup 1.0000x reference)
//
#include <hip/hip_runtime.h>

#define N_TEX 65536
#define C 16
#define U 4194304
#define ILP 4

typedef float f32x4 __attribute__((ext_vector_type(4)));

// 4 consecutive lanes per sample (one float4 of channels each) -> coalesced
// 1 KiB/wave output stores. Each thread handles ILP samples (grid-strided by
// total thread count) so 4 param loads + 8 gathers are in flight at once.
__global__ __launch_bounds__(256) void sampler1d_kernel(
    const f32x4* __restrict__ tex,    // [N_TEX][4] vectors
    const float* __restrict__ param,  // [U]
    f32x4*       __restrict__ out)    // [U][4]
{
    const int NT  = (U * 4) / ILP;                 // total threads = 4,194,304
    const int tid = blockIdx.x * 256 + threadIdx.x;
    const int q   = tid & 3;                       // same for all ILP iters (NT % 4 == 0)

    // Phase 1: param loads (independent, streamed once -> nontemporal)
    float p[ILP];
#pragma unroll
    for (int k = 0; k < ILP; ++k) {
        const int idx = tid + k * NT;
        p[k] = __builtin_nontemporal_load(&param[idx >> 2]);
    }

    // Phase 2: compute indices, issue all gathers (cached; texture stays in L2)
    float w[ILP];
    f32x4 a[ILP], b[ILP];
#pragma unroll
    for (int k = 0; k < ILP; ++k) {
        const float t = p[k] * (float)(N_TEX - 1);
        float f = floorf(t);
        f = fminf(fmaxf(f, 0.0f), (float)(N_TEX - 1));
        const int i0 = (int)f;
        const int i1 = min(i0 + 1, N_TEX - 1);
        w[k] = t - f;
        a[k] = tex[i0 * 4 + q];
        b[k] = tex[i1 * 4 + q];
    }

    // Phase 3: interpolate + nontemporal store (output streamed once)
#pragma unroll
    for (int k = 0; k < ILP; ++k) {
        const int idx = tid + k * NT;
        const float wk = w[k], iw = 1.0f - wk;
        f32x4 r = a[k] * iw + b[k] * wk;
        __builtin_nontemporal_store(r, &out[idx]);
    }
}

extern "C" void kernel_launch(void* const* d_in, const int* in_sizes, int n_in,
                              void* d_out, int out_size, void* d_ws, size_t ws_size,
                              hipStream_t stream) {
    const f32x4* tex   = (const f32x4*)d_in[0];
    const float* param = (const float*)d_in[1];
    f32x4*       out   = (f32x4*)d_out;

    const int total_thr = (U * 4) / ILP;            // 4,194,304
    const int block = 256;
    const int grid  = total_thr / block;            // 16,384 blocks
    sampler1d_kernel<<<grid, block, 0, stream>>>(tex, param, out);
}